// Round 1
// baseline (1575.465 us; speedup 1.0000x reference)
//
#include <hip/hip_runtime.h>
#include <hip/hip_bf16.h>

// ---------------- problem constants ----------------
#define NN      50000      // nodes
#define NE      500000     // edges (before self loops)
#define NET     550000     // edges + self loops
#define IND     256        // input dim
#define HC      512        // heads*hidden
#define NH      4          // heads
#define HD      128        // hidden per head
#define NG      512        // graphs
#define NCLS    10

// ---------------- helpers ----------------
__device__ __forceinline__ unsigned enc_f(float f) {
    unsigned u = __float_as_uint(f);
    return (u & 0x80000000u) ? ~u : (u | 0x80000000u);
}
__device__ __forceinline__ float dec_f(unsigned u) {
    return (u & 0x80000000u) ? __uint_as_float(u & 0x7fffffffu)
                             : __uint_as_float(~u);
}

// ---------------- fp32 tiled GEMM: C[M,N] = A[M,K] @ B[K,N] ----------------
// BM=BN=64, BK=16, 256 threads, 4x4 per thread.
__global__ __launch_bounds__(256) void k_gemm(const float* __restrict__ A,
                                              const float* __restrict__ B,
                                              float* __restrict__ C,
                                              int M, int N, int K) {
    __shared__ float As[16][64];
    __shared__ float Bs[16][64];
    const int tid = threadIdx.x;
    const int bm = blockIdx.x * 64, bn = blockIdx.y * 64;
    const int tx = tid & 15, ty = tid >> 4;
    const int lm = tid >> 2;          // 0..63   A row
    const int lk = (tid & 3) << 2;    // 0,4,8,12
    const int lbk = tid >> 4;         // 0..15   B row
    const int lbn = (tid & 15) << 2;  // 0..60
    float acc[4][4] = {};
    for (int k0 = 0; k0 < K; k0 += 16) {
        float4 av = make_float4(0.f, 0.f, 0.f, 0.f);
        int arow = bm + lm;
        if (arow < M) av = *(const float4*)&A[(size_t)arow * K + k0 + lk];
        As[lk + 0][lm] = av.x; As[lk + 1][lm] = av.y;
        As[lk + 2][lm] = av.z; As[lk + 3][lm] = av.w;
        *(float4*)&Bs[lbk][lbn] = *(const float4*)&B[(size_t)(k0 + lbk) * N + bn + lbn];
        __syncthreads();
#pragma unroll
        for (int k = 0; k < 16; ++k) {
            float4 a = *(const float4*)&As[k][ty << 2];
            float4 b = *(const float4*)&Bs[k][tx << 2];
            acc[0][0] += a.x * b.x; acc[0][1] += a.x * b.y; acc[0][2] += a.x * b.z; acc[0][3] += a.x * b.w;
            acc[1][0] += a.y * b.x; acc[1][1] += a.y * b.y; acc[1][2] += a.y * b.z; acc[1][3] += a.y * b.w;
            acc[2][0] += a.z * b.x; acc[2][1] += a.z * b.y; acc[2][2] += a.z * b.z; acc[2][3] += a.z * b.w;
            acc[3][0] += a.w * b.x; acc[3][1] += a.w * b.y; acc[3][2] += a.w * b.z; acc[3][3] += a.w * b.w;
        }
        __syncthreads();
    }
#pragma unroll
    for (int i = 0; i < 4; ++i) {
        int row = bm + (ty << 2) + i;
        if (row < M) {
            float4 v = make_float4(acc[i][0], acc[i][1], acc[i][2], acc[i][3]);
            *(float4*)&C[(size_t)row * N + bn + (tx << 2)] = v;
        }
    }
}

// ---------------- attention coefficients ----------------
// alpha_s[n,h] = dot(h[n, h*128:(h+1)*128], a_src[h]); same for dst.
// 256 threads = 2 nodes x 128 threads (each thread 4 features).
__global__ __launch_bounds__(256) void k_attn(const float* __restrict__ h,
                                              const float* __restrict__ a_src,
                                              const float* __restrict__ a_dst,
                                              float* __restrict__ as,
                                              float* __restrict__ ad, int N) {
    const int local = threadIdx.x & 127;
    const int node = blockIdx.x * 2 + (threadIdx.x >> 7);
    if (node >= N) return;
    const int head = local >> 5;
    const int c = (local & 31) << 2;
    float4 hv = *(const float4*)&h[(size_t)node * HC + (local << 2)];
    float4 sv = *(const float4*)&a_src[head * HD + c];
    float4 dv = *(const float4*)&a_dst[head * HD + c];
    float ps = hv.x * sv.x + hv.y * sv.y + hv.z * sv.z + hv.w * sv.w;
    float pd = hv.x * dv.x + hv.y * dv.y + hv.z * dv.z + hv.w * dv.w;
#pragma unroll
    for (int off = 16; off; off >>= 1) {
        ps += __shfl_down(ps, off, 32);
        pd += __shfl_down(pd, off, 32);
    }
    if ((local & 31) == 0) {
        as[node * NH + head] = ps;
        ad[node * NH + head] = pd;
    }
}

// ---------------- init m (encoded -FLT_MAX) ----------------
__global__ void k_init_m(unsigned* __restrict__ m, int n) {
    int i = blockIdx.x * blockDim.x + threadIdx.x;
    if (i < n) m[i] = enc_f(-3.0e38f);
}

// ---------------- edge max (segment max via encoded atomicMax) -------------
__global__ void k_edge_max(const int* __restrict__ ei,
                           const float* __restrict__ as,
                           const float* __restrict__ ad,
                           unsigned* __restrict__ m) {
    int e = blockIdx.x * blockDim.x + threadIdx.x;
    if (e >= NET) return;
    int s, d;
    if (e < NE) { s = ei[e]; d = ei[NE + e]; } else { s = d = e - NE; }
#pragma unroll
    for (int h = 0; h < NH; ++h) {
        float ev = as[s * NH + h] + ad[d * NH + h];
        ev = ev > 0.f ? ev : 0.2f * ev;
        atomicMax(&m[d * NH + h], enc_f(ev));
    }
}

__global__ void k_decode_m(unsigned* __restrict__ m, int n) {
    int i = blockIdx.x * blockDim.x + threadIdx.x;
    if (i < n) {
        float f = dec_f(m[i]);
        ((float*)m)[i] = f;
    }
}

// ---------------- edge exp-sum ----------------
__global__ void k_edge_expsum(const int* __restrict__ ei,
                              const float* __restrict__ as,
                              const float* __restrict__ ad,
                              const float* __restrict__ m,
                              float* __restrict__ denom) {
    int e = blockIdx.x * blockDim.x + threadIdx.x;
    if (e >= NET) return;
    int s, d;
    if (e < NE) { s = ei[e]; d = ei[NE + e]; } else { s = d = e - NE; }
#pragma unroll
    for (int h = 0; h < NH; ++h) {
        float ev = as[s * NH + h] + ad[d * NH + h];
        ev = ev > 0.f ? ev : 0.2f * ev;
        atomicAdd(&denom[d * NH + h], expf(ev - m[d * NH + h]));
    }
}

// ---------------- CSR build ----------------
__global__ void k_deg(const int* __restrict__ ei, int* __restrict__ deg) {
    int e = blockIdx.x * blockDim.x + threadIdx.x;
    if (e >= NET) return;
    int d = (e < NE) ? ei[NE + e] : (e - NE);
    atomicAdd(&deg[d], 1);
}

// single-block exclusive scan, n <= 50000; off has n+1 entries
__global__ __launch_bounds__(1024) void k_scan(const int* __restrict__ cnt,
                                               int* __restrict__ off, int n) {
    __shared__ int sums[1024];
    const int tid = threadIdx.x;
    const int chunk = (n + 1023) >> 10;
    const int beg = tid * chunk;
    const int end = min(beg + chunk, n);
    int s = 0;
    for (int i = beg; i < end; ++i) s += cnt[i];
    sums[tid] = s;
    __syncthreads();
    for (int d = 1; d < 1024; d <<= 1) {
        int t = (tid >= d) ? sums[tid - d] : 0;
        __syncthreads();
        sums[tid] += t;
        __syncthreads();
    }
    int run = (tid == 0) ? 0 : sums[tid - 1];
    for (int i = beg; i < end; ++i) { off[i] = run; run += cnt[i]; }
    if (tid == 1023) off[n] = sums[1023];
}

__global__ void k_fill(const int* __restrict__ ei,
                       const int* __restrict__ rowptr,
                       int* __restrict__ fillcnt,
                       int* __restrict__ colsrc) {
    int e = blockIdx.x * blockDim.x + threadIdx.x;
    if (e >= NET) return;
    int s, d;
    if (e < NE) { s = ei[e]; d = ei[NE + e]; } else { s = d = e - NE; }
    int pos = rowptr[d] + atomicAdd(&fillcnt[d], 1);
    colsrc[pos] = s;
}

// ---------------- aggregation: out[n] = relu(sum alpha*z[src] + b) --------
__global__ __launch_bounds__(128) void k_agg(const float* __restrict__ z,
                                             const float* __restrict__ as,
                                             const float* __restrict__ ad,
                                             const float* __restrict__ m,
                                             const float* __restrict__ denom,
                                             const int* __restrict__ rowptr,
                                             const int* __restrict__ colsrc,
                                             const float* __restrict__ bias,
                                             float* __restrict__ out) {
    __shared__ float lal[32][4];
    __shared__ int lsrc[32];
    const int n = blockIdx.x;
    const int tid = threadIdx.x;
    const int head = tid >> 5;
    const int beg = rowptr[n];
    const int deg = rowptr[n + 1] - beg;
    float4 acc = make_float4(0.f, 0.f, 0.f, 0.f);
    for (int chunk = 0; chunk < deg; chunk += 32) {
        int cnt = min(32, deg - chunk);
        if (tid < (cnt << 2)) {
            int el = tid >> 2, hh = tid & 3;
            int s = colsrc[beg + chunk + el];
            float ev = as[s * NH + hh] + ad[n * NH + hh];
            ev = ev > 0.f ? ev : 0.2f * ev;
            float al = expf(ev - m[n * NH + hh]) / (denom[n * NH + hh] + 1e-16f);
            lal[el][hh] = al;
            if (hh == 0) lsrc[el] = s;
        }
        __syncthreads();
        for (int el = 0; el < cnt; ++el) {
            float a = lal[el][head];
            float4 v = *(const float4*)&z[(size_t)lsrc[el] * HC + (tid << 2)];
            acc.x += a * v.x; acc.y += a * v.y; acc.z += a * v.z; acc.w += a * v.w;
        }
        __syncthreads();
    }
    float4 bv = *(const float4*)&bias[tid << 2];
    float4 r;
    r.x = fmaxf(acc.x + bv.x, 0.f);
    r.y = fmaxf(acc.y + bv.y, 0.f);
    r.z = fmaxf(acc.z + bv.z, 0.f);
    r.w = fmaxf(acc.w + bv.w, 0.f);
    *(float4*)&out[(size_t)n * HC + (tid << 2)] = r;
}

// ---------------- pooling ----------------
__global__ void k_gcnt(const int* __restrict__ batch, int* __restrict__ gcnt) {
    int n = blockIdx.x * blockDim.x + threadIdx.x;
    if (n < NN) atomicAdd(&gcnt[batch[n]], 1);
}

__global__ __launch_bounds__(128) void k_pool(const float* __restrict__ h,
                                              const int* __restrict__ goff,
                                              const int* __restrict__ gcnt,
                                              float* __restrict__ hg) {
    const int g = blockIdx.x;
    const int tid = threadIdx.x;
    const int beg = goff[g];
    const int cnt = gcnt[g];
    float4 acc = make_float4(0.f, 0.f, 0.f, 0.f);
    for (int r = beg; r < beg + cnt; ++r) {
        float4 v = *(const float4*)&h[(size_t)r * HC + (tid << 2)];
        acc.x += v.x; acc.y += v.y; acc.z += v.z; acc.w += v.w;
    }
    float inv = 1.0f / (float)max(cnt, 1);
    float4 o = make_float4(acc.x * inv, acc.y * inv, acc.z * inv, acc.w * inv);
    *(float4*)&hg[(size_t)g * HC + (tid << 2)] = o;
}

// ---------------- classifier: out[g,cls] = hg[g] . Wc[:,cls] + bc ----------
__global__ __launch_bounds__(64) void k_cls(const float* __restrict__ hg,
                                            const float* __restrict__ Wc,
                                            const float* __restrict__ bc,
                                            float* __restrict__ out) {
    const int g = blockIdx.x;
    const int lane = threadIdx.x;
#pragma unroll 1
    for (int cls = 0; cls < NCLS; ++cls) {
        float p = 0.f;
#pragma unroll
        for (int j = 0; j < 8; ++j) {
            int c = lane + j * 64;
            p += hg[(size_t)g * HC + c] * Wc[c * NCLS + cls];
        }
#pragma unroll
        for (int off = 32; off; off >>= 1) p += __shfl_down(p, off, 64);
        if (lane == 0) out[g * NCLS + cls] = p + bc[cls];
    }
}

// ---------------- launch ----------------
extern "C" void kernel_launch(void* const* d_in, const int* in_sizes, int n_in,
                              void* d_out, int out_size, void* d_ws, size_t ws_size,
                              hipStream_t stream) {
    const float* x     = (const float*)d_in[0];
    const int*   ei    = (const int*)d_in[1];
    const int*   batch = (const int*)d_in[2];
    const float* W1    = (const float*)d_in[3];
    const float* asrc1 = (const float*)d_in[4];
    const float* adst1 = (const float*)d_in[5];
    const float* b1    = (const float*)d_in[6];
    const float* W2    = (const float*)d_in[7];
    const float* asrc2 = (const float*)d_in[8];
    const float* adst2 = (const float*)d_in[9];
    const float* b2    = (const float*)d_in[10];
    const float* Wc    = (const float*)d_in[11];
    const float* bc    = (const float*)d_in[12];
    float* out = (float*)d_out;

    char* w = (char*)d_ws;
    size_t off = 0;
    auto alloc = [&](size_t bytes) {
        void* p = w + off;
        off += (bytes + 255) & ~(size_t)255;
        return p;
    };
    float* buf0   = (float*)alloc((size_t)NN * HC * 4);   // z (gemm out)
    float* buf1   = (float*)alloc((size_t)NN * HC * 4);   // h (agg out)
    float* as_b   = (float*)alloc((size_t)NN * NH * 4);
    float* ad_b   = (float*)alloc((size_t)NN * NH * 4);
    unsigned* m_b = (unsigned*)alloc((size_t)NN * NH * 4);
    float* den    = (float*)alloc((size_t)NN * NH * 4);
    int* rowptr   = (int*)alloc((size_t)(NN + 1) * 4);
    int* deg      = (int*)alloc((size_t)NN * 4);          // also reused as fillcnt
    int* colsrc   = (int*)alloc((size_t)NET * 4);
    int* gcnt     = (int*)alloc((size_t)NG * 4);
    int* goff     = (int*)alloc((size_t)(NG + 1) * 4);
    float* hg     = (float*)alloc((size_t)NG * HC * 4);
    (void)ws_size; (void)n_in; (void)in_sizes; (void)out_size;

    const int EB = 256, EG = (NET + EB - 1) / EB;

    // ---- CSR build (same for both layers) ----
    hipMemsetAsync(deg, 0, (size_t)NN * 4, stream);
    k_deg<<<EG, EB, 0, stream>>>(ei, deg);
    k_scan<<<1, 1024, 0, stream>>>(deg, rowptr, NN);
    hipMemsetAsync(deg, 0, (size_t)NN * 4, stream);   // reuse as fillcnt
    k_fill<<<EG, EB, 0, stream>>>(ei, rowptr, deg, colsrc);

    // ---- graph offsets ----
    hipMemsetAsync(gcnt, 0, (size_t)NG * 4, stream);
    k_gcnt<<<(NN + 255) / 256, 256, 0, stream>>>(batch, gcnt);
    k_scan<<<1, 1024, 0, stream>>>(gcnt, goff, NG);

    dim3 gemm_grid((NN + 63) / 64, HC / 64);

    // ================= layer 1 =================
    k_gemm<<<gemm_grid, 256, 0, stream>>>(x, W1, buf0, NN, HC, IND);
    k_attn<<<(NN + 1) / 2, 256, 0, stream>>>(buf0, asrc1, adst1, as_b, ad_b, NN);
    k_init_m<<<(NN * NH + 255) / 256, 256, 0, stream>>>(m_b, NN * NH);
    k_edge_max<<<EG, EB, 0, stream>>>(ei, as_b, ad_b, m_b);
    k_decode_m<<<(NN * NH + 255) / 256, 256, 0, stream>>>(m_b, NN * NH);
    hipMemsetAsync(den, 0, (size_t)NN * NH * 4, stream);
    k_edge_expsum<<<EG, EB, 0, stream>>>(ei, as_b, ad_b, (const float*)m_b, den);
    k_agg<<<NN, 128, 0, stream>>>(buf0, as_b, ad_b, (const float*)m_b, den,
                                  rowptr, colsrc, b1, buf1);

    // ================= layer 2 =================
    k_gemm<<<gemm_grid, 256, 0, stream>>>(buf1, W2, buf0, NN, HC, HC);
    k_attn<<<(NN + 1) / 2, 256, 0, stream>>>(buf0, asrc2, adst2, as_b, ad_b, NN);
    k_init_m<<<(NN * NH + 255) / 256, 256, 0, stream>>>(m_b, NN * NH);
    k_edge_max<<<EG, EB, 0, stream>>>(ei, as_b, ad_b, m_b);
    k_decode_m<<<(NN * NH + 255) / 256, 256, 0, stream>>>(m_b, NN * NH);
    hipMemsetAsync(den, 0, (size_t)NN * NH * 4, stream);
    k_edge_expsum<<<EG, EB, 0, stream>>>(ei, as_b, ad_b, (const float*)m_b, den);
    k_agg<<<NN, 128, 0, stream>>>(buf0, as_b, ad_b, (const float*)m_b, den,
                                  rowptr, colsrc, b2, buf1);

    // ================= pool + classify =================
    k_pool<<<NG, 128, 0, stream>>>(buf1, goff, gcnt, hg);
    k_cls<<<NG, 64, 0, stream>>>(hg, Wc, bc, out);
}

// Round 2
// 797.986 us; speedup vs baseline: 1.9743x; 1.9743x over previous
//
#include <hip/hip_runtime.h>

// ---------------- problem constants ----------------
#define NN      50000      // nodes
#define NE      500000     // edges (before self loops)
#define NET     550000     // edges + self loops
#define IND     256        // input dim
#define HC      512        // heads*hidden
#define NH      4          // heads
#define NG      512        // graphs
#define NCLS    10

typedef __attribute__((ext_vector_type(8))) short bf16x8;
typedef __attribute__((ext_vector_type(4))) float f32x4;

// ---------------- bf16 split helpers (RNE) ----------------
__device__ __forceinline__ ushort f2bf(float x) {
    unsigned u = __float_as_uint(x);
    u += 0x7fffu + ((u >> 16) & 1u);
    return (ushort)(u >> 16);
}
__device__ __forceinline__ float bf2f(ushort h) {
    return __uint_as_float((unsigned)h << 16);
}

// async global->LDS, 16B per lane. dst must be wave-uniform base (+lane*16 by HW).
__device__ __forceinline__ void gload_lds16(const void* g, void* s) {
    __builtin_amdgcn_global_load_lds(
        (const __attribute__((address_space(1))) unsigned*)g,
        (__attribute__((address_space(3))) unsigned*)s, 16, 0, 0);
}

// ---------------- split-bf16 MFMA GEMM ----------------
// C[M,512] = (Ahi+Alo)[M,K] @ (Bhi+Blo)[K,512]  (minus Alo*Blo, ~2^-18)
// computed as 3 K-segments: (Ahi,Bhi), (Ahi,Blo), (Alo,Bhi).
// B passed transposed: B*T[512][K].  BM=BN=128, BK=64, 256 thr = 4 waves (2x2),
// each wave 64x64 = 4x4 frags of 16x16x32.  LDS tiles [128][64] bf16,
// XOR-swizzled (chunk_col ^= row&7) via pre-swizzled global source.
__global__ __launch_bounds__(256) void k_gemm_mfma(
    const ushort* __restrict__ Ahi, const ushort* __restrict__ Alo,
    const ushort* __restrict__ BhiT, const ushort* __restrict__ BloT,
    float* __restrict__ C, int M, int K)
{
    __shared__ __align__(16) ushort As[128 * 64];
    __shared__ __align__(16) ushort Bs[128 * 64];

    const int tid = threadIdx.x;
    // bijective XCD swizzle (m204): nwg = 1564, not divisible by 8
    const int nwg = gridDim.x;
    const int orig = blockIdx.x;
    const int q = nwg >> 3, r = nwg & 7, xcd = orig & 7;
    const int wgid = (xcd < r ? xcd * (q + 1) : r * (q + 1) + (xcd - r) * q) + (orig >> 3);
    const int bm = (wgid >> 2) * 128;      // N-fastest: neighbors share A panel
    const int bn = (wgid & 3) * 128;

    const int l = tid & 63;
    const int w = tid >> 6;
    const int wm = (w >> 1) * 64, wn = (w & 1) * 64;
    const int fr = l & 15;            // row/col within fragment
    const int fk = (l >> 4) * 8;      // k offset within fragment (8 contiguous)

    f32x4 zero = {0.f, 0.f, 0.f, 0.f};
    f32x4 acc[4][4];
#pragma unroll
    for (int m = 0; m < 4; ++m)
#pragma unroll
        for (int n = 0; n < 4; ++n) acc[m][n] = zero;

    const int spseg = K >> 6;           // K-steps per segment
    const int total = 3 * spseg;
    const int wbase = (tid & 0xC0) << 4;  // wave-uniform byte base = wave*1024

    for (int ks = 0; ks < total; ++ks) {
        int seg = (ks >= spseg) + (ks >= 2 * spseg);
        int k0 = (ks - seg * spseg) << 6;
        const ushort* Ab = (seg == 2) ? Alo : Ahi;
        const ushort* Bb = (seg == 1) ? BloT : BhiT;
        // stage A tile 128x64 (16KB): 4 x 16B chunks per thread, LDS linear,
        // global source column pre-XOR'd so swizzled reads see logical data
#pragma unroll
        for (int i = 0; i < 4; ++i) {
            int c = i * 256 + tid;
            int row = c >> 3;
            int col16 = (c & 7) ^ (row & 7);
            int arow = bm + row; arow = arow < M ? arow : M - 1;   // clamp tail
            gload_lds16(Ab + (size_t)arow * K + k0 + (col16 << 3),
                        (char*)As + i * 4096 + wbase);
        }
#pragma unroll
        for (int i = 0; i < 4; ++i) {
            int c = i * 256 + tid;
            int j = c >> 3;
            int col16 = (c & 7) ^ (j & 7);
            gload_lds16(Bb + (size_t)(bn + j) * K + k0 + (col16 << 3),
                        (char*)Bs + i * 4096 + wbase);
        }
        __syncthreads();
#pragma unroll
        for (int kk = 0; kk < 64; kk += 32) {
            bf16x8 a[4], b[4];
            int kb = (kk + fk) >> 3;
#pragma unroll
            for (int m = 0; m < 4; ++m) {
                int row = wm + m * 16 + fr;
                a[m] = *(const bf16x8*)((const char*)As + row * 128 + ((kb ^ (row & 7)) << 4));
            }
#pragma unroll
            for (int n = 0; n < 4; ++n) {
                int col = wn + n * 16 + fr;
                b[n] = *(const bf16x8*)((const char*)Bs + col * 128 + ((kb ^ (col & 7)) << 4));
            }
#pragma unroll
            for (int m = 0; m < 4; ++m)
#pragma unroll
                for (int n = 0; n < 4; ++n)
                    acc[m][n] = __builtin_amdgcn_mfma_f32_16x16x32_bf16(a[m], b[n], acc[m][n], 0, 0, 0);
        }
        __syncthreads();
    }

    // C/D layout: col = lane&15, row = (lane>>4)*4 + reg   [verified m89/m91]
    const int rbase = (l >> 4) * 4;
#pragma unroll
    for (int m = 0; m < 4; ++m) {
        int row0 = bm + wm + m * 16 + rbase;
#pragma unroll
        for (int n = 0; n < 4; ++n) {
            int col = bn + wn + n * 16 + fr;
#pragma unroll
            for (int rr = 0; rr < 4; ++rr) {
                int rowi = row0 + rr;
                if (rowi < M) C[(size_t)rowi * HC + col] = acc[m][n][rr];
            }
        }
    }
}

// ---------------- conversions ----------------
__global__ void k_cvt_hilo(const float* __restrict__ in, ushort* __restrict__ hi,
                           ushort* __restrict__ lo, int n4) {
    int i = blockIdx.x * blockDim.x + threadIdx.x;
    if (i >= n4) return;
    float4 v = ((const float4*)in)[i];
    ushort4 h, l;
    h.x = f2bf(v.x); l.x = f2bf(v.x - bf2f(h.x));
    h.y = f2bf(v.y); l.y = f2bf(v.y - bf2f(h.y));
    h.z = f2bf(v.z); l.z = f2bf(v.z - bf2f(h.z));
    h.w = f2bf(v.w); l.w = f2bf(v.w - bf2f(h.w));
    ((ushort4*)hi)[i] = h;
    ((ushort4*)lo)[i] = l;
}

// W[K][512] -> hiT/loT[512][K] (transposed so GEMM B-frags are K-contiguous)
__global__ void k_cvt_wT(const float* __restrict__ W, ushort* __restrict__ hiT,
                         ushort* __restrict__ loT, int K, int logK) {
    int id = blockIdx.x * blockDim.x + threadIdx.x;
    if (id >= (HC << logK)) return;
    int nn = id >> logK, k = id & (K - 1);
    float x = W[(size_t)k * HC + nn];
    ushort h = f2bf(x);
    hiT[id] = h;
    loT[id] = f2bf(x - bf2f(h));
}

// ---------------- attention coefficients ----------------
__global__ __launch_bounds__(256) void k_attn(const float* __restrict__ h,
                                              const float* __restrict__ a_src,
                                              const float* __restrict__ a_dst,
                                              float* __restrict__ as,
                                              float* __restrict__ ad, int N) {
    const int local = threadIdx.x & 127;
    const int node = blockIdx.x * 2 + (threadIdx.x >> 7);
    if (node >= N) return;
    const int head = local >> 5;
    const int c = (local & 31) << 2;
    float4 hv = *(const float4*)&h[(size_t)node * HC + (local << 2)];
    float4 sv = *(const float4*)&a_src[head * 128 + c];
    float4 dv = *(const float4*)&a_dst[head * 128 + c];
    float ps = hv.x * sv.x + hv.y * sv.y + hv.z * sv.z + hv.w * sv.w;
    float pd = hv.x * dv.x + hv.y * dv.y + hv.z * dv.z + hv.w * dv.w;
#pragma unroll
    for (int off = 16; off; off >>= 1) {
        ps += __shfl_down(ps, off, 32);
        pd += __shfl_down(pd, off, 32);
    }
    if ((local & 31) == 0) {
        as[node * NH + head] = ps;
        ad[node * NH + head] = pd;
    }
}

// ---------------- CSR build ----------------
__global__ void k_deg(const int* __restrict__ ei, int* __restrict__ deg) {
    int e = blockIdx.x * blockDim.x + threadIdx.x;
    if (e >= NET) return;
    int d = (e < NE) ? ei[NE + e] : (e - NE);
    atomicAdd(&deg[d], 1);
}

__global__ __launch_bounds__(1024) void k_scan(const int* __restrict__ cnt,
                                               int* __restrict__ off, int n) {
    __shared__ int sums[1024];
    const int tid = threadIdx.x;
    const int chunk = (n + 1023) >> 10;
    const int beg = tid * chunk;
    const int end = min(beg + chunk, n);
    int s = 0;
    for (int i = beg; i < end; ++i) s += cnt[i];
    sums[tid] = s;
    __syncthreads();
    for (int d = 1; d < 1024; d <<= 1) {
        int t = (tid >= d) ? sums[tid - d] : 0;
        __syncthreads();
        sums[tid] += t;
        __syncthreads();
    }
    int run = (tid == 0) ? 0 : sums[tid - 1];
    for (int i = beg; i < end; ++i) { off[i] = run; run += cnt[i]; }
    if (tid == 1023) off[n] = sums[1023];
}

__global__ void k_fill(const int* __restrict__ ei,
                       const int* __restrict__ rowptr,
                       int* __restrict__ fillcnt,
                       int* __restrict__ colsrc) {
    int e = blockIdx.x * blockDim.x + threadIdx.x;
    if (e >= NET) return;
    int s, d;
    if (e < NE) { s = ei[e]; d = ei[NE + e]; } else { s = d = e - NE; }
    int pos = rowptr[d] + atomicAdd(&fillcnt[d], 1);
    colsrc[pos] = s;
}

// ---------------- fused softmax + aggregation ----------------
// per node: pass1 max, pass2 expsum (shfl+LDS reduce), pass3 gather-accumulate.
// mode 0: fp32 out; mode 1: bf16 hi/lo out (feeds next GEMM directly).
__global__ __launch_bounds__(128) void k_agg(
    const float* __restrict__ z, const float* __restrict__ as,
    const float* __restrict__ ad, const int* __restrict__ rowptr,
    const int* __restrict__ colsrc, const float* __restrict__ bias,
    float* __restrict__ outf, ushort* __restrict__ ohi,
    ushort* __restrict__ olo, int mode)
{
    __shared__ float lal[32][4];
    __shared__ int lsrc[32];
    __shared__ float wred[2][4];
    const int n = blockIdx.x;
    const int tid = threadIdx.x;
    const int beg = rowptr[n], end = rowptr[n + 1];
    const int h4 = tid & 3;                 // head (edge phases & pass3 staging)
    const float adn = ad[n * 4 + h4];

    // pass 1: segment max (every node has >=1 edge: self-loop)
    float lm = -3.0e38f;
    for (int e = beg + (tid >> 2); e < end; e += 32) {
        int s = colsrc[e];
        float ev = as[s * 4 + h4] + adn;
        ev = ev > 0.f ? ev : 0.2f * ev;
        lm = fmaxf(lm, ev);
    }
#pragma unroll
    for (int off = 4; off < 64; off <<= 1) lm = fmaxf(lm, __shfl_xor(lm, off, 64));
    if ((tid & 63) < 4) wred[tid >> 6][h4] = lm;
    __syncthreads();
    const float mh = fmaxf(wred[0][h4], wred[1][h4]);
    __syncthreads();

    // pass 2: exp-sum
    float ls = 0.f;
    for (int e = beg + (tid >> 2); e < end; e += 32) {
        int s = colsrc[e];
        float ev = as[s * 4 + h4] + adn;
        ev = ev > 0.f ? ev : 0.2f * ev;
        ls += __expf(ev - mh);
    }
#pragma unroll
    for (int off = 4; off < 64; off <<= 1) ls += __shfl_xor(ls, off, 64);
    if ((tid & 63) < 4) wred[tid >> 6][h4] = ls;
    __syncthreads();
    const float dinv = 1.0f / (wred[0][h4] + wred[1][h4] + 1e-16f);

    // pass 3: weighted feature gather
    const int hdr = tid >> 5;               // head for feature columns
    float4 acc = make_float4(0.f, 0.f, 0.f, 0.f);
    for (int chunk = beg; chunk < end; chunk += 32) {
        int cnt = min(32, end - chunk);
        __syncthreads();
        if (tid < (cnt << 2)) {
            int el = tid >> 2;
            int s = colsrc[chunk + el];
            float ev = as[s * 4 + h4] + adn;
            ev = ev > 0.f ? ev : 0.2f * ev;
            lal[el][h4] = __expf(ev - mh) * dinv;
            if (h4 == 0) lsrc[el] = s;
        }
        __syncthreads();
        for (int el = 0; el < cnt; ++el) {
            float a = lal[el][hdr];
            float4 v = *(const float4*)&z[(size_t)lsrc[el] * HC + (tid << 2)];
            acc.x += a * v.x; acc.y += a * v.y; acc.z += a * v.z; acc.w += a * v.w;
        }
    }
    float4 bv = *(const float4*)&bias[tid << 2];
    float rx = fmaxf(acc.x + bv.x, 0.f), ry = fmaxf(acc.y + bv.y, 0.f);
    float rz = fmaxf(acc.z + bv.z, 0.f), rw = fmaxf(acc.w + bv.w, 0.f);
    if (mode == 0) {
        *(float4*)&outf[(size_t)n * HC + (tid << 2)] = make_float4(rx, ry, rz, rw);
    } else {
        ushort4 h, l;
        h.x = f2bf(rx); l.x = f2bf(rx - bf2f(h.x));
        h.y = f2bf(ry); l.y = f2bf(ry - bf2f(h.y));
        h.z = f2bf(rz); l.z = f2bf(rz - bf2f(h.z));
        h.w = f2bf(rw); l.w = f2bf(rw - bf2f(h.w));
        *(ushort4*)&ohi[(size_t)n * HC + (tid << 2)] = h;
        *(ushort4*)&olo[(size_t)n * HC + (tid << 2)] = l;
    }
}

// ---------------- pooling / classifier ----------------
__global__ void k_gcnt(const int* __restrict__ batch, int* __restrict__ gcnt) {
    int n = blockIdx.x * blockDim.x + threadIdx.x;
    if (n < NN) atomicAdd(&gcnt[batch[n]], 1);
}

__global__ __launch_bounds__(128) void k_pool(const float* __restrict__ h,
                                              const int* __restrict__ goff,
                                              const int* __restrict__ gcnt,
                                              float* __restrict__ hg) {
    const int g = blockIdx.x;
    const int tid = threadIdx.x;
    const int beg = goff[g];
    const int cnt = gcnt[g];
    float4 acc = make_float4(0.f, 0.f, 0.f, 0.f);
    for (int r = beg; r < beg + cnt; ++r) {
        float4 v = *(const float4*)&h[(size_t)r * HC + (tid << 2)];
        acc.x += v.x; acc.y += v.y; acc.z += v.z; acc.w += v.w;
    }
    float inv = 1.0f / (float)max(cnt, 1);
    *(float4*)&hg[(size_t)g * HC + (tid << 2)] =
        make_float4(acc.x * inv, acc.y * inv, acc.z * inv, acc.w * inv);
}

__global__ __launch_bounds__(64) void k_cls(const float* __restrict__ hg,
                                            const float* __restrict__ Wc,
                                            const float* __restrict__ bc,
                                            float* __restrict__ out) {
    const int g = blockIdx.x;
    const int lane = threadIdx.x;
#pragma unroll 1
    for (int cls = 0; cls < NCLS; ++cls) {
        float p = 0.f;
#pragma unroll
        for (int j = 0; j < 8; ++j) {
            int c = lane + j * 64;
            p += hg[(size_t)g * HC + c] * Wc[c * NCLS + cls];
        }
#pragma unroll
        for (int off = 32; off; off >>= 1) p += __shfl_down(p, off, 64);
        if (lane == 0) out[g * NCLS + cls] = p + bc[cls];
    }
}

// ---------------- launch ----------------
extern "C" void kernel_launch(void* const* d_in, const int* in_sizes, int n_in,
                              void* d_out, int out_size, void* d_ws, size_t ws_size,
                              hipStream_t stream) {
    const float* x     = (const float*)d_in[0];
    const int*   ei    = (const int*)d_in[1];
    const int*   batch = (const int*)d_in[2];
    const float* W1    = (const float*)d_in[3];
    const float* asrc1 = (const float*)d_in[4];
    const float* adst1 = (const float*)d_in[5];
    const float* b1    = (const float*)d_in[6];
    const float* W2    = (const float*)d_in[7];
    const float* asrc2 = (const float*)d_in[8];
    const float* adst2 = (const float*)d_in[9];
    const float* b2    = (const float*)d_in[10];
    const float* Wc    = (const float*)d_in[11];
    const float* bc    = (const float*)d_in[12];
    float* out = (float*)d_out;
    (void)in_sizes; (void)n_in; (void)out_size; (void)ws_size;

    char* w = (char*)d_ws;
    size_t off = 0;
    auto alloc = [&](size_t bytes) {
        void* p = w + off;
        off += (bytes + 255) & ~(size_t)255;
        return p;
    };
    float* bufA = (float*)alloc((size_t)NN * HC * 4);      // z (GEMM out), 102.4 MB
    char*  bufB = (char*)alloc((size_t)NN * HC * 4);       // time-shared region, 102.4 MB
    // region B lifetimes (strictly sequential on stream):
    //   [cvt..GEMM1]  xhi @ +0 (25.6M), xlo @ +25.6M
    //   [agg1..GEMM2] h1hi @ +0 (51.2M), h1lo @ +51.2M
    //   [agg2..pool]  h2 fp32 @ +0 (102.4M)
    ushort* xhi  = (ushort*)(bufB);
    ushort* xlo  = (ushort*)(bufB + (size_t)NN * IND * 2);
    ushort* h1hi = (ushort*)(bufB);
    ushort* h1lo = (ushort*)(bufB + (size_t)NN * HC * 2);
    float*  h2f  = (float*)(bufB);

    float* as_b = (float*)alloc((size_t)NN * NH * 4);
    float* ad_b = (float*)alloc((size_t)NN * NH * 4);
    int* rowptr = (int*)alloc((size_t)(NN + 1) * 4);
    int* deg    = (int*)alloc((size_t)NN * 4);             // reused as fillcnt
    int* colsrc = (int*)alloc((size_t)NET * 4);
    int* gcnt   = (int*)alloc((size_t)NG * 4);
    int* goff   = (int*)alloc((size_t)(NG + 1) * 4);
    float* hg   = (float*)alloc((size_t)NG * HC * 4);
    ushort* B1hiT = (ushort*)alloc((size_t)HC * IND * 2);
    ushort* B1loT = (ushort*)alloc((size_t)HC * IND * 2);
    ushort* B2hiT = (ushort*)alloc((size_t)HC * HC * 2);
    ushort* B2loT = (ushort*)alloc((size_t)HC * HC * 2);

    const int EB = 256, EG = (NET + EB - 1) / EB;
    const int MT = (NN + 127) / 128;                       // 391 M-tiles

    // ---- conversions ----
    k_cvt_hilo<<<(NN * IND / 4 + 255) / 256, 256, 0, stream>>>(x, xhi, xlo, NN * IND / 4);
    k_cvt_wT<<<(HC * IND + 255) / 256, 256, 0, stream>>>(W1, B1hiT, B1loT, IND, 8);
    k_cvt_wT<<<(HC * HC + 255) / 256, 256, 0, stream>>>(W2, B2hiT, B2loT, HC, 9);

    // ---- CSR build ----
    hipMemsetAsync(deg, 0, (size_t)NN * 4, stream);
    k_deg<<<EG, EB, 0, stream>>>(ei, deg);
    k_scan<<<1, 1024, 0, stream>>>(deg, rowptr, NN);
    hipMemsetAsync(deg, 0, (size_t)NN * 4, stream);
    k_fill<<<EG, EB, 0, stream>>>(ei, rowptr, deg, colsrc);

    // ---- graph offsets ----
    hipMemsetAsync(gcnt, 0, (size_t)NG * 4, stream);
    k_gcnt<<<(NN + 255) / 256, 256, 0, stream>>>(batch, gcnt);
    k_scan<<<1, 1024, 0, stream>>>(gcnt, goff, NG);

    // ================= layer 1 =================
    k_gemm_mfma<<<MT * 4, 256, 0, stream>>>(xhi, xlo, B1hiT, B1loT, bufA, NN, IND);
    k_attn<<<(NN + 1) / 2, 256, 0, stream>>>(bufA, asrc1, adst1, as_b, ad_b, NN);
    k_agg<<<NN, 128, 0, stream>>>(bufA, as_b, ad_b, rowptr, colsrc, b1,
                                  h2f, h1hi, h1lo, 1);

    // ================= layer 2 =================
    k_gemm_mfma<<<MT * 4, 256, 0, stream>>>(h1hi, h1lo, B2hiT, B2loT, bufA, NN, HC);
    k_attn<<<(NN + 1) / 2, 256, 0, stream>>>(bufA, asrc2, adst2, as_b, ad_b, NN);
    k_agg<<<NN, 128, 0, stream>>>(bufA, as_b, ad_b, rowptr, colsrc, b2,
                                  h2f, h1hi, h1lo, 0);

    // ================= pool + classify =================
    k_pool<<<NG, 128, 0, stream>>>(h2f, goff, gcnt, hg);
    k_cls<<<NG, 64, 0, stream>>>(hg, Wc, bc, out);
}